// Round 4
// baseline (1808.775 us; speedup 1.0000x reference)
//
#include <hip/hip_runtime.h>
#include <cstdint>
#include <cstddef>

#define BB 512
#define TT 1024
#define FF 128
#define HH 128
#define AA 16

// Barrier that does NOT drain vmcnt (keeps x prefetch in flight).
#define BAR() asm volatile("s_waitcnt lgkmcnt(0)\n\ts_barrier" ::: "memory")

typedef float f32x2 __attribute__((ext_vector_type(2)));

__device__ __forceinline__ float rl(float v, int l) {
    return __int_as_float(__builtin_amdgcn_readlane(__float_as_int(v), l));
}

// 512 threads = 8 waves, one block per batch element.
//  C-waves (0-3): LIF1 + cur2 half-chain (u=(wid>>1)&1) in phase A;
//                 LIF2 + ballot -> mw2s in phase B. State for h=lane, 64+lane
//                 replicated per wave so ballots give mask words in-wave.
//  P-waves (4-7): phase A: cur1 chains for step st+1 (q=wid&3, x via
//                 readlane) AND out-partials p3 for step st-1 (from mw2s,
//                 W3 row in 16 VGPRs; waves duplicate in pairs for SIMD
//                 balance); wave 4 lanes<16 do the o-sum + store in phase B.
// All FP summation DAGs identical to the previous passing kernels:
//  cur1 = ((s0+s1)+(s2+s3))+b1 ; s_q = fmaf chain k ascending over x[4k+q]
//  cur2 = c2a+c2b ; c2a = b2 then word0,word2 ascending ; c2b = word1,word3
//  out  = b3 + p3[0..7] sequential ; p3[g] = 16-term fmaf chain ascending
// (fmaf(0,w,c)==c and fmaf(1,w,c)==c+w exactly).
__global__ __launch_bounds__(512, 4) void dsqn_fused(
    const float* __restrict__ X,      // (B,T,F)
    const float* __restrict__ hid,    // (B,1,2,H)
    const float* __restrict__ W1,     // (H,F)
    const float* __restrict__ b1,     // (H)
    const float* __restrict__ beta1,  // (H)
    const float* __restrict__ W2,     // (H,H)
    const float* __restrict__ b2,     // (H)
    const float* __restrict__ beta2,  // (H)
    const float* __restrict__ W3,     // (A,H)
    const float* __restrict__ b3,     // (A)
    float* __restrict__ out)          // (B,T,A)
{
    __shared__ float p1b[2][4 * HH];   // [parity][q*128+h] cur1 partials
    __shared__ float p2[2 * HH];       // [u*128+j] cur2 half-chains
    __shared__ float p3[128];          // out partials (step st-1)
    __shared__ unsigned mw2s[4];       // spike-2 mask words

    const int t = threadIdx.x;
    const int b = blockIdx.x;
    const int lane = t & 63;
    const int wid = t >> 6;            // 0..7
    const bool isC2 = (wid < 4);
    const int u = (wid >> 1) & 1;      // C-waves: chain half
    const int q = wid & 3;             // P-waves: cur1 chain index

    // ---- union weight registers (pinned into arch VGPRs) ----
    f32x2 wv[32];                      // C: (W2[j][k], W2[j][64+k]) ; P: (W1[lane][4k+q], W1[64+lane][4k+q])
    float w3r[16];                     // P only: W3 row r3
    int r3 = 0;
    if (isC2) {
        const float* w2p = W2 + (t & 127) * HH + u * 32;
        #pragma unroll
        for (int k = 0; k < 32; ++k) { wv[k].x = w2p[k]; wv[k].y = w2p[64 + k]; }
    } else {
        const float* wa = W1 + lane * FF + q;
        const float* wb = W1 + (64 + lane) * FF + q;
        #pragma unroll
        for (int k = 0; k < 32; ++k) { wv[k].x = wa[4 * k]; wv[k].y = wb[4 * k]; }
        r3 = ((wid & 1) << 6) | lane;  // waves 4,6: rows 0..63 ; 5,7: 64..127
        const int a3 = r3 & 15, g3 = r3 >> 4;
        const float* w3p = W3 + a3 * HH + g3 * 16;
        #pragma unroll
        for (int k = 0; k < 16; ++k) w3r[k] = w3p[k];
        #pragma unroll
        for (int k = 0; k < 16; ++k) asm volatile("" : "+v"(w3r[k]));
    }
    #pragma unroll
    for (int k = 0; k < 32; ++k) asm volatile("" : "+v"(wv[k]));

    // ---- per-thread state (C-waves only) ----
    float mem1_0 = 0.f, mem1_1 = 0.f, mem2_0 = 0.f, mem2_1 = 0.f;
    float b1h0 = 0.f, b1h1 = 0.f, bt1_0 = 0.f, bt1_1 = 0.f;
    float b2j = 0.f, bt2_0 = 0.f, bt2_1 = 0.f;
    if (isC2) {
        mem1_0 = hid[b * 2 * HH + lane];
        mem1_1 = hid[b * 2 * HH + 64 + lane];
        mem2_0 = hid[b * 2 * HH + HH + lane];
        mem2_1 = hid[b * 2 * HH + HH + 64 + lane];
        b1h0 = b1[lane]; b1h1 = b1[64 + lane];
        bt1_0 = fminf(fmaxf(beta1[lane], 0.f), 1.f);
        bt1_1 = fminf(fmaxf(beta1[64 + lane], 0.f), 1.f);
        b2j = b2[t & 127];
        bt2_0 = fminf(fmaxf(beta2[lane], 0.f), 1.f);
        bt2_1 = fminf(fmaxf(beta2[64 + lane], 0.f), 1.f);
    }
    float b3a = 0.f;
    if (wid == 4) b3a = b3[lane & 15];

    const float* xrow = X + (size_t)b * TT * FF;
    float* orow = out + (size_t)b * TT * AA;
    const int xidx = 4 * (lane & 31) + q;   // lane k holds x[4k+q]
    float xv = 0.f;

    if (t == 0) { mw2s[0] = 0u; mw2s[1] = 0u; mw2s[2] = 0u; mw2s[3] = 0u; }

    if (!isC2) {
        // prologue: p1 for step 0 from x[0]; xv = x[1]
        const float xv0 = xrow[xidx];
        float a0 = 0.f, a1 = 0.f;
        #pragma unroll
        for (int k = 0; k < 32; ++k) {
            const float xs = rl(xv0, k);
            a0 = fmaf(xs, wv[k].x, a0);
            a1 = fmaf(xs, wv[k].y, a1);
        }
        p1b[0][q * 128 + lane] = a0;
        p1b[0][q * 128 + 64 + lane] = a1;
        xv = xrow[FF + xidx];
    }
    BAR();

    for (int st = 0; st < TT; ++st) {
        const int par = st & 1;

        if (isC2) {
            // ---- phase A: LIF1 + cur2 half-chain ----
            const float* p1c = p1b[par];
            const float c00 = p1c[lane],       c01 = p1c[128 + lane];
            const float c02 = p1c[256 + lane], c03 = p1c[384 + lane];
            const float c10 = p1c[64 + lane],  c11 = p1c[192 + lane];
            const float c12 = p1c[320 + lane], c13 = p1c[448 + lane];
            const float cur1_0 = ((c00 + c01) + (c02 + c03)) + b1h0;
            const float cur1_1 = ((c10 + c11) + (c12 + c13)) + b1h1;
            const float r1_0 = (mem1_0 > 1.0f) ? 1.0f : 0.0f;
            const float r1_1 = (mem1_1 > 1.0f) ? 1.0f : 0.0f;
            mem1_0 = bt1_0 * mem1_0 + cur1_0 - r1_0;
            mem1_1 = bt1_1 * mem1_1 + cur1_1 - r1_1;
            const unsigned long long balA = __ballot((mem1_0 - 1.0f) > 0.0f); // words 0,1
            const unsigned long long balB = __ballot((mem1_1 - 1.0f) > 0.0f); // words 2,3

            // lanes 0-31 = bits of word u ; lanes 32-63 = bits of word 2+u
            const unsigned wlo = u ? (unsigned)(balA >> 32) : (unsigned)balA;
            const unsigned whi = u ? (unsigned)(balB >> 32) : (unsigned)balB;
            const unsigned long long packed =
                (unsigned long long)wlo | ((unsigned long long)whi << 32);
            const float mflt = ((unsigned)(packed >> lane) & 1u) ? 1.0f : 0.0f;

            float c = u ? 0.f : b2j;
            #pragma unroll
            for (int k = 0; k < 32; ++k) c = fmaf(rl(mflt, k), wv[k].x, c);
            #pragma unroll
            for (int k = 0; k < 32; ++k) c = fmaf(rl(mflt, 32 + k), wv[k].y, c);
            p2[u * 128 + (t & 127)] = c;
        } else {
            // ---- phase A: cur1 chains for step st+1 ----
            float a0 = 0.f, a1 = 0.f;
            #pragma unroll
            for (int k = 0; k < 32; ++k) {
                const float xs = rl(xv, k);
                a0 = fmaf(xs, wv[k].x, a0);
                a1 = fmaf(xs, wv[k].y, a1);
            }
            float* p1n = p1b[par ^ 1];
            p1n[q * 128 + lane] = a0;
            p1n[q * 128 + 64 + lane] = a1;

            // ---- out partials for step st-1 (st==0: masks zeroed, discarded)
            {
                const unsigned w0m = mw2s[0], w1m = mw2s[1];
                const unsigned w2m = mw2s[2], w3m = mw2s[3];
                const int g = r3 >> 4;
                const int wi = r3 >> 5;
                const unsigned word = (wi == 0) ? w0m : (wi == 1) ? w1m
                                    : (wi == 2) ? w2m : w3m;
                const unsigned chunk = (word >> ((g & 1) * 16)) & 0xFFFFu;
                float p = 0.f;
                #pragma unroll
                for (int k = 0; k < 16; ++k) {
                    const float m = ((chunk >> k) & 1u) ? 1.0f : 0.0f;
                    p = fmaf(m, w3r[k], p);
                }
                p3[r3] = p;   // waves duplicate in pairs: same value, benign
            }
            // prefetch x[st+2]; barriers never drain vmcnt
            xv = (st + 2 < TT) ? xrow[2 * FF + xidx] : 0.f;
            xrow += FF;
        }
        BAR();  // B: p2, p1(next), p3(st-1) visible

        if (isC2) {
            // ---- phase B: LIF2 + ballot -> mw2s ----
            const float cur2_0 = p2[lane] + p2[128 + lane];
            const float cur2_1 = p2[64 + lane] + p2[192 + lane];
            const float r2_0 = (mem2_0 > 1.0f) ? 1.0f : 0.0f;
            const float r2_1 = (mem2_1 > 1.0f) ? 1.0f : 0.0f;
            mem2_0 = bt2_0 * mem2_0 + cur2_0 - r2_0;
            mem2_1 = bt2_1 * mem2_1 + cur2_1 - r2_1;
            const unsigned long long balC = __ballot((mem2_0 - 1.0f) > 0.0f); // words 0,1
            const unsigned long long balD = __ballot((mem2_1 - 1.0f) > 0.0f); // words 2,3
            if (t == 0) {
                mw2s[0] = (unsigned)balC; mw2s[1] = (unsigned)(balC >> 32);
                mw2s[2] = (unsigned)balD; mw2s[3] = (unsigned)(balD >> 32);
            }
        } else if (wid == 4 && lane < AA && st) {
            // ---- phase B: o-sum + store for step st-1 ----
            float o = b3a;
            #pragma unroll
            for (int gg = 0; gg < 8; ++gg) o += p3[gg * 16 + lane];
            orow[(st - 1) * AA + lane] = o;
        }
        BAR();  // C: mw2s visible; p3 readers done
    }

    // ---- epilogue: out(TT-1) ----
    if (!isC2) {
        const unsigned w0m = mw2s[0], w1m = mw2s[1];
        const unsigned w2m = mw2s[2], w3m = mw2s[3];
        const int g = r3 >> 4;
        const int wi = r3 >> 5;
        const unsigned word = (wi == 0) ? w0m : (wi == 1) ? w1m
                            : (wi == 2) ? w2m : w3m;
        const unsigned chunk = (word >> ((g & 1) * 16)) & 0xFFFFu;
        float p = 0.f;
        #pragma unroll
        for (int k = 0; k < 16; ++k) {
            const float m = ((chunk >> k) & 1u) ? 1.0f : 0.0f;
            p = fmaf(m, w3r[k], p);
        }
        p3[r3] = p;
    }
    BAR();
    if (wid == 4 && lane < AA) {
        float o = b3a;
        #pragma unroll
        for (int gg = 0; gg < 8; ++gg) o += p3[gg * 16 + lane];
        orow[(TT - 1) * AA + lane] = o;
    }
}

extern "C" void kernel_launch(void* const* d_in, const int* in_sizes, int n_in,
                              void* d_out, int out_size, void* d_ws, size_t ws_size,
                              hipStream_t stream) {
    const float* X     = (const float*)d_in[0];
    const float* hid   = (const float*)d_in[1];
    const float* W1    = (const float*)d_in[2];
    const float* b1    = (const float*)d_in[3];
    const float* beta1 = (const float*)d_in[4];
    const float* W2    = (const float*)d_in[5];
    const float* b2    = (const float*)d_in[6];
    const float* beta2 = (const float*)d_in[7];
    const float* W3    = (const float*)d_in[8];
    const float* b3    = (const float*)d_in[9];
    float* out = (float*)d_out;

    dsqn_fused<<<BB, 512, 0, stream>>>(X, hid, W1, b1, beta1, W2, b2, beta2, W3, b3, out);
}